// Round 15
// baseline (422.845 us; speedup 1.0000x reference)
//
#include <hip/hip_runtime.h>
#include <math.h>

#define BB 8
#define CC 3
#define HH 256
#define WW 256
#define KSZ 37
#define PD 18

#define DWT_OFF 0
#define GAB_OFF (8*12*128*128)                 /* 1572864 */
#define FFT_OFF (GAB_OFF + 8*54*256*256)       /* 29884416 */

#define PSTRIDE 88   /* patch row stride in bf16 elems */

#define PREP_BLOCKS 888     /* 888*512 = 454656 exactly */
#define FFTROW_BLOCKS 768   /* 6144 rows / 8 waves */
#define GAB_BLOCKS 3072     /* 64 tiles * 24 images * 2 shift-halves */
#define FFTCOL_BLOCKS 774   /* 3096 live cols (24*129) / 4 waves — tail */

typedef short bf16x8 __attribute__((ext_vector_type(8)));
typedef float f32x16 __attribute__((ext_vector_type(16)));

__device__ __forceinline__ unsigned f2bf(float f) {
  unsigned u = __float_as_uint(f);
  return (u + 0x7fffu + ((u >> 16) & 1u)) >> 16;   // RNE bf16
}

// ================================================================ K1
// blocks [0,888): filter prep (coalesced layout wshc[s][ky][t][lane][8])
// blocks [888,1656): row FFTs; re->mag cols 0..128, im->phase cols 0..128;
// zero-fills pad cols 129..255 so pass B handles live cols only.
__global__ __launch_bounds__(512) void fused_pre_kernel(
    const float* __restrict__ x, const float* __restrict__ wk,
    ushort* __restrict__ wshc, float* __restrict__ out) {
  __shared__ __align__(16) float smem[4352];   // re 2048 | im 2048 | tw 256
  const int g = blockIdx.x;
  const int tid = threadIdx.x;

  if (g < PREP_BLOCKS) {
    int idx = g * 512 + tid;                   // < 454656
    int j = idx & 7; int rest = idx >> 3;
    int l = rest & 63; rest >>= 6;
    int t = rest % 3; rest /= 3;
    int ky = rest % 37; int s = rest / 37;
    int m = l & 31, hi = l >> 5;
    int kk = 16 * t + 8 * hi + j - s;
    float v = 0.0f;
    if (m < 18 && kk >= 0 && kk < 37) v = wk[(m * 37 + ky) * 37 + kk];
    wshc[idx] = (ushort)f2bf(v);
    return;
  }

  const int w = tid >> 6;
  const int t = tid & 63;
  const int rowid = (g - PREP_BLOCKS) * 8 + w;     // [0, 6144)
  float* re  = smem + w * 256;
  float* im  = smem + 2048 + w * 256;
  float* twr = smem + 4096;
  float* twi = smem + 4224;

#pragma unroll
  for (int q = 0; q < 2; ++q) {
    int k = t + q * 64;
    float sn, cs;
    sincosf(-2.0f * (float)M_PI * (float)k / 256.0f, &sn, &cs);
    twr[k] = cs; twi[k] = sn;
  }
  const float* xr = x + (size_t)rowid * 256;
#pragma unroll
  for (int q = 0; q < 4; ++q) {
    int i = t + q * 64;
    int br = __brev((unsigned)i) >> 24;
    re[br] = xr[i];
    im[br] = 0.0f;
  }
  for (int s = 1; s <= 8; ++s) {
    int half = 1 << (s - 1);
    int sh = 8 - s;
#pragma unroll
    for (int q = 0; q < 2; ++q) {
      int j = t + q * 64;
      int gg = j >> (s - 1);
      int p = j & (half - 1);
      int i1 = (gg << s) + p;
      int i2 = i1 + half;
      float cs = twr[p << sh], sn = twi[p << sh];
      float r2 = re[i2], m2 = im[i2];
      float tr = r2 * cs - m2 * sn;
      float ti = r2 * sn + m2 * cs;
      float r1 = re[i1], m1 = im[i1];
      re[i2] = r1 - tr; im[i2] = m1 - ti;
      re[i1] = r1 + tr; im[i1] = m1 + ti;
    }
  }
  const int bc = rowid >> 8;                  // b*3 + c
  const int y  = rowid & 255;
  const int b  = bc / 3, c = bc - b * 3;
  float* magrow = out + FFT_OFF + (size_t)(b * 6 + c) * (HH * WW) + (size_t)y * WW;
  float* phrow  = magrow + (size_t)3 * (HH * WW);
#pragma unroll
  for (int q = 0; q < 2; ++q) {
    int k = t + q * 64;
    magrow[k] = re[k];
    phrow[k]  = im[k];
  }
  if (t == 0) { magrow[128] = re[128]; phrow[128] = im[128]; }
  magrow[129 + t] = 0.0f;
  phrow[129 + t]  = 0.0f;
  if (t < 63) {
    magrow[193 + t] = 0.0f;
    phrow[193 + t]  = 0.0f;
  }
}

// ================================================================ K2
// blocks [0,3072): Gabor conv, 256-thr (4 waves), FULL A+B ping-pong.
//   Tile 32x32 split across 2 blocks by shift parity: block half h covers
//   output x = 8j + s for s in [4h, 4h+4); wave w -> shift s = 4h + w.
//   12 waves/CU (3 blocks, <=170 regs) + register renaming breaks the
//   WAR hazard that serialized LDS reads behind MFMAs.
// blocks [3072,3846): column FFTs, live cols only, 4 cols/block tail.
#define LOAD_B(S, P) \
    r##S##0 = *reinterpret_cast<const bf16x8*>(P); \
    r##S##1 = *reinterpret_cast<const bf16x8*>((P) + 8); \
    r##S##2 = *reinterpret_cast<const bf16x8*>((P) + 16); \
    r##S##3 = *reinterpret_cast<const bf16x8*>((P) + 24); \
    r##S##4 = *reinterpret_cast<const bf16x8*>((P) + 32); \
    r##S##5 = *reinterpret_cast<const bf16x8*>((P) + 40); \
    r##S##6 = *reinterpret_cast<const bf16x8*>((P) + 48); \
    r##S##7 = *reinterpret_cast<const bf16x8*>((P) + 56);
#define LOAD_A(S, P) \
    a##S##0 = *reinterpret_cast<const bf16x8*>(P); \
    a##S##1 = *reinterpret_cast<const bf16x8*>((P) + 512); \
    a##S##2 = *reinterpret_cast<const bf16x8*>((P) + 1024);
#define MFMA_GROUP(S) \
    acc0 = __builtin_amdgcn_mfma_f32_32x32x16_bf16(a##S##0, r##S##0, acc0, 0, 0, 0); \
    acc1 = __builtin_amdgcn_mfma_f32_32x32x16_bf16(a##S##0, r##S##1, acc1, 0, 0, 0); \
    acc2 = __builtin_amdgcn_mfma_f32_32x32x16_bf16(a##S##0, r##S##2, acc2, 0, 0, 0); \
    acc3 = __builtin_amdgcn_mfma_f32_32x32x16_bf16(a##S##0, r##S##3, acc3, 0, 0, 0); \
    acc0 = __builtin_amdgcn_mfma_f32_32x32x16_bf16(a##S##1, r##S##2, acc0, 0, 0, 0); \
    acc1 = __builtin_amdgcn_mfma_f32_32x32x16_bf16(a##S##1, r##S##3, acc1, 0, 0, 0); \
    acc2 = __builtin_amdgcn_mfma_f32_32x32x16_bf16(a##S##1, r##S##4, acc2, 0, 0, 0); \
    acc3 = __builtin_amdgcn_mfma_f32_32x32x16_bf16(a##S##1, r##S##5, acc3, 0, 0, 0); \
    acc0 = __builtin_amdgcn_mfma_f32_32x32x16_bf16(a##S##2, r##S##4, acc0, 0, 0, 0); \
    acc1 = __builtin_amdgcn_mfma_f32_32x32x16_bf16(a##S##2, r##S##5, acc1, 0, 0, 0); \
    acc2 = __builtin_amdgcn_mfma_f32_32x32x16_bf16(a##S##2, r##S##6, acc2, 0, 0, 0); \
    acc3 = __builtin_amdgcn_mfma_f32_32x32x16_bf16(a##S##2, r##S##7, acc3, 0, 0, 0);

__global__ __launch_bounds__(256, 3) void fused_main_kernel(
    const float* __restrict__ x, const ushort* __restrict__ wshc,
    float* __restrict__ out) {
  __shared__ __align__(16) float smem[7216];
  const int g = blockIdx.x;
  const int tid = threadIdx.x;

  if (g < GAB_BLOCKS) {
    // ------------------------------------------------ Gabor conv (MFMA)
    unsigned* patchU = reinterpret_cast<unsigned*>(smem);  // 68*44 uints
    float* cbuf = smem + 2992;                             // 4*32*33 floats
    const int half = g & 1;
    const int tile = (g >> 1) & 63;
    const int img  = g >> 7;                               // [0,24)
    const int cin = img % 3, b = img / 3;
    const int tileX = (tile & 7) * 32;
    const int tileY = (tile >> 3) * 32;
    const float* xp = x + (size_t)(b * CC + cin) * (HH * WW);

    for (int idx = tid; idx < 68 * (PSTRIDE / 2); idx += 256) {
      int r = idx / (PSTRIDE / 2), dc = idx - r * (PSTRIDE / 2);
      int gy = tileY + r - PD;
      int gx0 = tileX + 2 * dc - PD;
      float v0 = 0.0f, v1 = 0.0f;
      if ((unsigned)gy < 256u) {
        if ((unsigned)gx0 < 256u)       v0 = xp[gy * WW + gx0];
        if ((unsigned)(gx0 + 1) < 256u) v1 = xp[gy * WW + gx0 + 1];
      }
      patchU[idx] = f2bf(v0) | (f2bf(v1) << 16);
    }
    __syncthreads();

    const int w  = tid >> 6;      // wave 0..3
    const int s  = 4 * half + w;  // shift role 0..7
    const int l  = tid & 63;
    const int n  = l & 31;
    const int hi = l >> 5;

    f32x16 acc0 = {0.f,0.f,0.f,0.f,0.f,0.f,0.f,0.f,0.f,0.f,0.f,0.f,0.f,0.f,0.f,0.f};
    f32x16 acc1 = acc0, acc2 = acc0, acc3 = acc0;

    const ushort* patchS = reinterpret_cast<const ushort*>(patchU);
    const ushort* ap = wshc + (size_t)s * (37 * 3 * 512) + (size_t)l * 8;
    const ushort* bp = patchS + (size_t)n * PSTRIDE + hi * 8;

    bf16x8 aA0, aA1, aA2, aB0, aB1, aB2;
    bf16x8 rA0, rA1, rA2, rA3, rA4, rA5, rA6, rA7;
    bf16x8 rB0, rB1, rB2, rB3, rB4, rB5, rB6, rB7;

    LOAD_A(A, ap)
    LOAD_B(A, bp)
    for (int kp = 0; kp < 18; ++kp) {
      // even ky = 2kp: prefetch (A,B)(ky+1) into set B, compute set A
      LOAD_A(B, ap + 1536)
      LOAD_B(B, bp + PSTRIDE)
      MFMA_GROUP(A)
      // odd ky = 2kp+1: prefetch (A,B)(ky+2) into set A, compute set B
      LOAD_A(A, ap + 3072)
      LOAD_B(A, bp + 2 * PSTRIDE)
      MFMA_GROUP(B)
      ap += 3072;
      bp += 2 * PSTRIDE;
    }
    MFMA_GROUP(A)                                  // ky = 36
    __syncthreads();

    // ---- epilogue: C row f' = (e&3)+8*(e>>2)+4*hi, col n; via cbuf.
    // Block writes only its 4 shift-columns; stores x = 8j + s.
    float* outb = out + GAB_OFF + (size_t)(b * 54 + cin * 18) * (HH * WW);
#pragma unroll
    for (int gq = 0; gq < 5; ++gq) {
      if (hi == (gq & 1)) {
        const int rq = gq >> 1;
#pragma unroll
        for (int q = 0; q < 4; ++q) {
          const int e = 4 * rq + q;
          float* crow = &cbuf[(q * 32 + n) * 33 + s];
          crow[0]  = acc0[e];
          crow[8]  = acc1[e];
          crow[16] = acc2[e];
          crow[24] = acc3[e];
        }
      }
      __syncthreads();
#pragma unroll
      for (int it = 0; it < 8; ++it) {
        int idx = tid + it * 256;                  // 2048 = 4f x 32y x 16x
        int xs = idx & 15, yo = (idx >> 4) & 31, fq = idx >> 9;
        int xo = (xs >> 2) * 8 + (xs & 3) + 4 * half;
        int f = 4 * gq + fq;
        if (f < 18)
          outb[(size_t)f * (HH * WW) + (size_t)(tileY + yo) * WW + tileX + xo] =
              cbuf[(fq * 32 + yo) * 33 + xo];
      }
      __syncthreads();
    }
    return;
  }

  // ---- column FFT + mag/phase, live cols only (one wave per column)
  const int w = tid >> 6;
  const int t = tid & 63;
  const int colid = (g - GAB_BLOCKS) * 4 + w;      // [0, 3096)
  const int bc = colid / 129;                      // [0, 24)
  const int k  = colid - bc * 129;                 // [0, 129)
  const int b  = bc / 3, c = bc - b * 3;
  float* re  = smem + w * 512;
  float* im  = smem + w * 512 + 256;
  float* twr = smem + 2048;
  float* twi = smem + 2176;

#pragma unroll
  for (int q = 0; q < 2; ++q) {
    int kk = t + q * 64;
    float sn, cs;
    sincosf(-2.0f * (float)M_PI * (float)kk / 256.0f, &sn, &cs);
    twr[kk] = cs; twi[kk] = sn;
  }

  float* magp = out + FFT_OFF + (size_t)(b * 6 + c) * (HH * WW);
  float* php  = magp + (size_t)3 * (HH * WW);
#pragma unroll
  for (int q = 0; q < 4; ++q) {
    int y = t + q * 64;
    int br = __brev((unsigned)y) >> 24;
    re[br] = magp[(size_t)y * WW + k];
    im[br] = php[(size_t)y * WW + k];
  }

  for (int s = 1; s <= 8; ++s) {
    int half = 1 << (s - 1);
    int sh = 8 - s;
#pragma unroll
    for (int q = 0; q < 2; ++q) {
      int j = t + q * 64;
      int gg = j >> (s - 1);
      int p = j & (half - 1);
      int i1 = (gg << s) + p;
      int i2 = i1 + half;
      float cs = twr[p << sh], sn = twi[p << sh];
      float r2 = re[i2], m2 = im[i2];
      float tr = r2 * cs - m2 * sn;
      float ti = r2 * sn + m2 * cs;
      float r1 = re[i1], m1 = im[i1];
      re[i2] = r1 - tr; im[i2] = m1 - ti;
      re[i1] = r1 + tr; im[i1] = m1 + ti;
    }
  }

  const float scale = 1.0f / 256.0f;   // ortho: /sqrt(256*256)
#pragma unroll
  for (int q = 0; q < 4; ++q) {
    int u = t + q * 64;
    float r = re[u], m = im[u];
    magp[(size_t)u * WW + k] = sqrtf(r * r + m * m) * scale;
    php[(size_t)u * WW + k]  = atan2f(m, r);
  }
}

// ================================================================ K3: DWT
__global__ __launch_bounds__(256) void haar_dwt_kernel(
    const float* __restrict__ x, float* __restrict__ out) {
  int idx = blockIdx.x * 256 + threadIdx.x;
  if (idx >= BB * CC * 128 * 128) return;
  int j  = idx & 127;
  int i  = (idx >> 7) & 127;
  int bc = idx >> 14;
  const float* xp = x + (size_t)bc * (HH * WW);
  float2 top = *reinterpret_cast<const float2*>(&xp[(2 * i) * WW + 2 * j]);
  float2 bot = *reinterpret_cast<const float2*>(&xp[(2 * i + 1) * WW + 2 * j]);
  float a = top.x, b = top.y, c = bot.x, d = bot.y;
  int bI = bc / 3, cI = bc % 3;
  float* op = out + DWT_OFF + ((size_t)(bI * 12 + cI * 4) * 128 + i) * 128 + j;
  op[0]     = (a + b + c + d) * 0.5f;
  op[16384] = (a + b - c - d) * 0.5f;
  op[32768] = (a - b + c - d) * 0.5f;
  op[49152] = (a - b - c + d) * 0.5f;
}

// ----------------------------------------------------------------
extern "C" void kernel_launch(void* const* d_in, const int* in_sizes, int n_in,
                              void* d_out, int out_size, void* d_ws, size_t ws_size,
                              hipStream_t stream) {
  const float* x  = (const float*)d_in[0];
  const float* wk = (const float*)d_in[1];
  float* out = (float*)d_out;

  // wshc scratch lives in the DWT output region; DWT (K3) runs last.
  ushort* wshc = (ushort*)(out + DWT_OFF);       // 909 KB

  fused_pre_kernel<<<dim3(PREP_BLOCKS + FFTROW_BLOCKS), dim3(512), 0, stream>>>(
      x, wk, wshc, out);
  fused_main_kernel<<<dim3(GAB_BLOCKS + FFTCOL_BLOCKS), dim3(256), 0, stream>>>(
      x, wshc, out);
  haar_dwt_kernel<<<dim3(1536), dim3(256), 0, stream>>>(x, out);
}

// Round 16
// 167.453 us; speedup vs baseline: 2.5252x; 2.5252x over previous
//
#include <hip/hip_runtime.h>
#include <math.h>

#define BB 8
#define CC 3
#define HH 256
#define WW 256
#define KSZ 37
#define PD 18

#define DWT_OFF 0
#define GAB_OFF (8*12*128*128)                 /* 1572864 */
#define FFT_OFF (GAB_OFF + 8*54*256*256)       /* 29884416 */

#define PSTRIDE 88   /* patch row stride in bf16 elems */

#define PREP_BLOCKS 888     /* 888*512 = 454656 exactly */
#define FFTROW_BLOCKS 768   /* 6144 rows / 8 waves */
#define GAB_BLOCKS 1536
#define FFTCOL_BLOCKS 387   /* 3096 live cols (24*129) / 8 waves — tail */

typedef short bf16x8 __attribute__((ext_vector_type(8)));
typedef float f32x16 __attribute__((ext_vector_type(16)));

__device__ __forceinline__ unsigned f2bf(float f) {
  unsigned u = __float_as_uint(f);
  return (u + 0x7fffu + ((u >> 16) & 1u)) >> 16;   // RNE bf16
}

// ================================================================ K1
// blocks [0,888): filter prep (coalesced layout wshc[s][ky][t][lane][8])
// blocks [888,1656): row FFTs, one wave per image row; re->mag plane
// cols 0..128, im->phase plane cols 0..128; ALSO zero-fills pad cols
// 129..255 of both planes (coalesced) so pass B handles live cols only.
__global__ __launch_bounds__(512) void fused_pre_kernel(
    const float* __restrict__ x, const float* __restrict__ wk,
    ushort* __restrict__ wshc, float* __restrict__ out) {
  __shared__ __align__(16) float smem[4352];   // re 2048 | im 2048 | tw 256
  const int g = blockIdx.x;
  const int tid = threadIdx.x;

  if (g < PREP_BLOCKS) {
    int idx = g * 512 + tid;                   // < 454656
    int j = idx & 7; int rest = idx >> 3;
    int l = rest & 63; rest >>= 6;
    int t = rest % 3; rest /= 3;
    int ky = rest % 37; int s = rest / 37;
    int m = l & 31, hi = l >> 5;
    int kk = 16 * t + 8 * hi + j - s;
    float v = 0.0f;
    if (m < 18 && kk >= 0 && kk < 37) v = wk[(m * 37 + ky) * 37 + kk];
    wshc[idx] = (ushort)f2bf(v);
    return;
  }

  const int w = tid >> 6;
  const int t = tid & 63;
  const int rowid = (g - PREP_BLOCKS) * 8 + w;     // [0, 6144)
  float* re  = smem + w * 256;
  float* im  = smem + 2048 + w * 256;
  float* twr = smem + 4096;
  float* twi = smem + 4224;

#pragma unroll
  for (int q = 0; q < 2; ++q) {
    int k = t + q * 64;
    float sn, cs;
    sincosf(-2.0f * (float)M_PI * (float)k / 256.0f, &sn, &cs);
    twr[k] = cs; twi[k] = sn;
  }
  const float* xr = x + (size_t)rowid * 256;
#pragma unroll
  for (int q = 0; q < 4; ++q) {
    int i = t + q * 64;
    int br = __brev((unsigned)i) >> 24;
    re[br] = xr[i];
    im[br] = 0.0f;
  }
  for (int s = 1; s <= 8; ++s) {
    int half = 1 << (s - 1);
    int sh = 8 - s;
#pragma unroll
    for (int q = 0; q < 2; ++q) {
      int j = t + q * 64;
      int gg = j >> (s - 1);
      int p = j & (half - 1);
      int i1 = (gg << s) + p;
      int i2 = i1 + half;
      float cs = twr[p << sh], sn = twi[p << sh];
      float r2 = re[i2], m2 = im[i2];
      float tr = r2 * cs - m2 * sn;
      float ti = r2 * sn + m2 * cs;
      float r1 = re[i1], m1 = im[i1];
      re[i2] = r1 - tr; im[i2] = m1 - ti;
      re[i1] = r1 + tr; im[i1] = m1 + ti;
    }
  }
  const int bc = rowid >> 8;                  // b*3 + c
  const int y  = rowid & 255;
  const int b  = bc / 3, c = bc - b * 3;
  float* magrow = out + FFT_OFF + (size_t)(b * 6 + c) * (HH * WW) + (size_t)y * WW;
  float* phrow  = magrow + (size_t)3 * (HH * WW);
#pragma unroll
  for (int q = 0; q < 2; ++q) {
    int k = t + q * 64;
    magrow[k] = re[k];
    phrow[k]  = im[k];
  }
  if (t == 0) { magrow[128] = re[128]; phrow[128] = im[128]; }
  // zero-fill pad cols 129..255 (never touched by pass B)
  magrow[129 + t] = 0.0f;
  phrow[129 + t]  = 0.0f;
  if (t < 63) {
    magrow[193 + t] = 0.0f;
    phrow[193 + t]  = 0.0f;
  }
}

// ================================================================ K2
// blocks [0,1536): Gabor conv via MFMA (R7/R8 structure, A ping-pong).
// blocks [1536,1923): column FFTs, LIVE columns only (k<129), tail.
#define LOAD_B_SET \
    r0 = *reinterpret_cast<const bf16x8*>(bp); \
    r1 = *reinterpret_cast<const bf16x8*>(bp + 8); \
    r2 = *reinterpret_cast<const bf16x8*>(bp + 16); \
    r3 = *reinterpret_cast<const bf16x8*>(bp + 24); \
    r4 = *reinterpret_cast<const bf16x8*>(bp + 32); \
    r5 = *reinterpret_cast<const bf16x8*>(bp + 40); \
    r6 = *reinterpret_cast<const bf16x8*>(bp + 48); \
    r7 = *reinterpret_cast<const bf16x8*>(bp + 56);
#define MFMA_GROUP(A0, A1, A2) \
    acc0 = __builtin_amdgcn_mfma_f32_32x32x16_bf16(A0, r0, acc0, 0, 0, 0); \
    acc1 = __builtin_amdgcn_mfma_f32_32x32x16_bf16(A0, r1, acc1, 0, 0, 0); \
    acc2 = __builtin_amdgcn_mfma_f32_32x32x16_bf16(A0, r2, acc2, 0, 0, 0); \
    acc3 = __builtin_amdgcn_mfma_f32_32x32x16_bf16(A0, r3, acc3, 0, 0, 0); \
    acc0 = __builtin_amdgcn_mfma_f32_32x32x16_bf16(A1, r2, acc0, 0, 0, 0); \
    acc1 = __builtin_amdgcn_mfma_f32_32x32x16_bf16(A1, r3, acc1, 0, 0, 0); \
    acc2 = __builtin_amdgcn_mfma_f32_32x32x16_bf16(A1, r4, acc2, 0, 0, 0); \
    acc3 = __builtin_amdgcn_mfma_f32_32x32x16_bf16(A1, r5, acc3, 0, 0, 0); \
    acc0 = __builtin_amdgcn_mfma_f32_32x32x16_bf16(A2, r4, acc0, 0, 0, 0); \
    acc1 = __builtin_amdgcn_mfma_f32_32x32x16_bf16(A2, r5, acc1, 0, 0, 0); \
    acc2 = __builtin_amdgcn_mfma_f32_32x32x16_bf16(A2, r6, acc2, 0, 0, 0); \
    acc3 = __builtin_amdgcn_mfma_f32_32x32x16_bf16(A2, r7, acc3, 0, 0, 0);

__global__ __launch_bounds__(512, 4) void fused_main_kernel(
    const float* __restrict__ x, const ushort* __restrict__ wshc,
    float* __restrict__ out) {
  __shared__ __align__(16) float smem[7216];
  const int g = blockIdx.x;
  const int tid = threadIdx.x;

  if (g < GAB_BLOCKS) {
    // ------------------------------------------------ Gabor conv (MFMA)
    unsigned* patchU = reinterpret_cast<unsigned*>(smem);  // 68*44 uints
    float* cbuf = smem + 2992;                             // 4*32*33 floats
    const int tile = g & 63;
    const int rest = g >> 6;                               // [0,24)
    const int cin = rest % 3, b = rest / 3;
    const int tileX = (tile & 7) * 32;
    const int tileY = (tile >> 3) * 32;
    const float* xp = x + (size_t)(b * CC + cin) * (HH * WW);

    for (int idx = tid; idx < 68 * (PSTRIDE / 2); idx += 512) {
      int r = idx / (PSTRIDE / 2), dc = idx - r * (PSTRIDE / 2);
      int gy = tileY + r - PD;
      int gx0 = tileX + 2 * dc - PD;
      float v0 = 0.0f, v1 = 0.0f;
      if ((unsigned)gy < 256u) {
        if ((unsigned)gx0 < 256u)       v0 = xp[gy * WW + gx0];
        if ((unsigned)(gx0 + 1) < 256u) v1 = xp[gy * WW + gx0 + 1];
      }
      patchU[idx] = f2bf(v0) | (f2bf(v1) << 16);
    }
    __syncthreads();

    const int w  = tid >> 6;
    const int l  = tid & 63;
    const int n  = l & 31;
    const int hi = l >> 5;

    f32x16 acc0 = {0.f,0.f,0.f,0.f,0.f,0.f,0.f,0.f,0.f,0.f,0.f,0.f,0.f,0.f,0.f,0.f};
    f32x16 acc1 = acc0, acc2 = acc0, acc3 = acc0;

    const ushort* patchS = reinterpret_cast<const ushort*>(patchU);
    const ushort* ap = wshc + (size_t)w * (37 * 3 * 512) + (size_t)l * 8;
    const ushort* bp = patchS + (size_t)n * PSTRIDE + hi * 8;

    bf16x8 aA0, aA1, aA2, aB0, aB1, aB2;
    bf16x8 r0, r1, r2, r3, r4, r5, r6, r7;

    aA0 = *reinterpret_cast<const bf16x8*>(ap);
    aA1 = *reinterpret_cast<const bf16x8*>(ap + 512);
    aA2 = *reinterpret_cast<const bf16x8*>(ap + 1024);

    for (int kp = 0; kp < 18; ++kp) {
      aB0 = *reinterpret_cast<const bf16x8*>(ap + 1536);
      aB1 = *reinterpret_cast<const bf16x8*>(ap + 2048);
      aB2 = *reinterpret_cast<const bf16x8*>(ap + 2560);
      LOAD_B_SET
      MFMA_GROUP(aA0, aA1, aA2)
      bp += PSTRIDE;
      aA0 = *reinterpret_cast<const bf16x8*>(ap + 3072);
      aA1 = *reinterpret_cast<const bf16x8*>(ap + 3584);
      aA2 = *reinterpret_cast<const bf16x8*>(ap + 4096);
      LOAD_B_SET
      MFMA_GROUP(aB0, aB1, aB2)
      ap += 3072;
      bp += PSTRIDE;
    }
    {
      LOAD_B_SET
      MFMA_GROUP(aA0, aA1, aA2)
    }
    __syncthreads();

    float* outb = out + GAB_OFF + (size_t)(b * 54 + cin * 18) * (HH * WW);
#pragma unroll
    for (int gq = 0; gq < 5; ++gq) {
      if (hi == (gq & 1)) {
        const int rq = gq >> 1;
#pragma unroll
        for (int q = 0; q < 4; ++q) {
          const int e = 4 * rq + q;
          float* crow = &cbuf[(q * 32 + n) * 33 + w];
          crow[0]  = acc0[e];
          crow[8]  = acc1[e];
          crow[16] = acc2[e];
          crow[24] = acc3[e];
        }
      }
      __syncthreads();
#pragma unroll
      for (int it = 0; it < 8; ++it) {
        int idx = tid + it * 512;
        int xo = idx & 31, yo = (idx >> 5) & 31, q = idx >> 10;
        int f = 4 * gq + q;
        if (f < 18)
          outb[(size_t)f * (HH * WW) + (size_t)(tileY + yo) * WW + tileX + xo] =
              cbuf[(q * 32 + yo) * 33 + xo];
      }
      __syncthreads();
    }
    return;
  }

  // ---- column FFT + mag/phase, live cols only (one wave per column)
  const int w = tid >> 6;
  const int t = tid & 63;
  const int colid = (g - GAB_BLOCKS) * 8 + w;      // [0, 3096)
  const int bc = colid / 129;                      // [0, 24)
  const int k  = colid - bc * 129;                 // [0, 129)
  const int b  = bc / 3, c = bc - b * 3;
  float* re  = smem + w * 256;
  float* im  = smem + 2048 + w * 256;
  float* twr = smem + 4096;
  float* twi = smem + 4224;

#pragma unroll
  for (int q = 0; q < 2; ++q) {
    int kk = t + q * 64;
    float sn, cs;
    sincosf(-2.0f * (float)M_PI * (float)kk / 256.0f, &sn, &cs);
    twr[kk] = cs; twi[kk] = sn;
  }

  float* magp = out + FFT_OFF + (size_t)(b * 6 + c) * (HH * WW);
  float* php  = magp + (size_t)3 * (HH * WW);
#pragma unroll
  for (int q = 0; q < 4; ++q) {
    int y = t + q * 64;
    int br = __brev((unsigned)y) >> 24;
    re[br] = magp[(size_t)y * WW + k];
    im[br] = php[(size_t)y * WW + k];
  }

  for (int s = 1; s <= 8; ++s) {
    int half = 1 << (s - 1);
    int sh = 8 - s;
#pragma unroll
    for (int q = 0; q < 2; ++q) {
      int j = t + q * 64;
      int gg = j >> (s - 1);
      int p = j & (half - 1);
      int i1 = (gg << s) + p;
      int i2 = i1 + half;
      float cs = twr[p << sh], sn = twi[p << sh];
      float r2 = re[i2], m2 = im[i2];
      float tr = r2 * cs - m2 * sn;
      float ti = r2 * sn + m2 * cs;
      float r1 = re[i1], m1 = im[i1];
      re[i2] = r1 - tr; im[i2] = m1 - ti;
      re[i1] = r1 + tr; im[i1] = m1 + ti;
    }
  }

  const float scale = 1.0f / 256.0f;   // ortho: /sqrt(256*256)
#pragma unroll
  for (int q = 0; q < 4; ++q) {
    int u = t + q * 64;
    float r = re[u], m = im[u];
    magp[(size_t)u * WW + k] = sqrtf(r * r + m * m) * scale;
    php[(size_t)u * WW + k]  = atan2f(m, r);
  }
}

// ================================================================ K3: DWT
__global__ __launch_bounds__(256) void haar_dwt_kernel(
    const float* __restrict__ x, float* __restrict__ out) {
  int idx = blockIdx.x * 256 + threadIdx.x;
  if (idx >= BB * CC * 128 * 128) return;
  int j  = idx & 127;
  int i  = (idx >> 7) & 127;
  int bc = idx >> 14;
  const float* xp = x + (size_t)bc * (HH * WW);
  float2 top = *reinterpret_cast<const float2*>(&xp[(2 * i) * WW + 2 * j]);
  float2 bot = *reinterpret_cast<const float2*>(&xp[(2 * i + 1) * WW + 2 * j]);
  float a = top.x, b = top.y, c = bot.x, d = bot.y;
  int bI = bc / 3, cI = bc % 3;
  float* op = out + DWT_OFF + ((size_t)(bI * 12 + cI * 4) * 128 + i) * 128 + j;
  op[0]     = (a + b + c + d) * 0.5f;
  op[16384] = (a + b - c - d) * 0.5f;
  op[32768] = (a - b + c - d) * 0.5f;
  op[49152] = (a - b - c + d) * 0.5f;
}

// ----------------------------------------------------------------
extern "C" void kernel_launch(void* const* d_in, const int* in_sizes, int n_in,
                              void* d_out, int out_size, void* d_ws, size_t ws_size,
                              hipStream_t stream) {
  const float* x  = (const float*)d_in[0];
  const float* wk = (const float*)d_in[1];
  float* out = (float*)d_out;

  // wshc scratch lives in the DWT output region; DWT (K3) runs last.
  ushort* wshc = (ushort*)(out + DWT_OFF);       // 909 KB

  fused_pre_kernel<<<dim3(PREP_BLOCKS + FFTROW_BLOCKS), dim3(512), 0, stream>>>(
      x, wk, wshc, out);
  fused_main_kernel<<<dim3(GAB_BLOCKS + FFTCOL_BLOCKS), dim3(512), 0, stream>>>(
      x, wshc, out);
  haar_dwt_kernel<<<dim3(1536), dim3(256), 0, stream>>>(x, out);
}

// Round 17
// 157.499 us; speedup vs baseline: 2.6847x; 1.0632x over previous
//
#include <hip/hip_runtime.h>
#include <math.h>

#define BB 8
#define CC 3
#define HH 256
#define WW 256
#define KSZ 37
#define PD 18

#define DWT_OFF 0
#define GAB_OFF (8*12*128*128)                 /* 1572864 */
#define FFT_OFF (GAB_OFF + 8*54*256*256)       /* 29884416 */

#define PSTRIDE 88   /* patch row stride in bf16 elems */

#define PREP_BLOCKS 888     /* 888*512 = 454656 exactly */
#define FFTROW_BLOCKS 768   /* 6144 rows / 8 waves */
#define GAB_BLOCKS 1536
#define FFTCOL_BLOCKS 408   /* 24 images * 17 eight-col panels — tail */

typedef short bf16x8 __attribute__((ext_vector_type(8)));
typedef float f32x16 __attribute__((ext_vector_type(16)));

__device__ __forceinline__ unsigned f2bf(float f) {
  unsigned u = __float_as_uint(f);
  return (u + 0x7fffu + ((u >> 16) & 1u)) >> 16;   // RNE bf16
}

// ================================================================ K1
// blocks [0,888): filter prep (coalesced layout wshc[s][ky][t][lane][8])
// blocks [888,1656): row FFTs, one wave per image row; re->mag plane
// cols 0..128, im->phase plane cols 0..128; ALSO zero-fills pad cols
// 129..255 of both planes (coalesced) so pass B handles live cols only.
__global__ __launch_bounds__(512) void fused_pre_kernel(
    const float* __restrict__ x, const float* __restrict__ wk,
    ushort* __restrict__ wshc, float* __restrict__ out) {
  __shared__ __align__(16) float smem[4352];   // re 2048 | im 2048 | tw 256
  const int g = blockIdx.x;
  const int tid = threadIdx.x;

  if (g < PREP_BLOCKS) {
    int idx = g * 512 + tid;                   // < 454656
    int j = idx & 7; int rest = idx >> 3;
    int l = rest & 63; rest >>= 6;
    int t = rest % 3; rest /= 3;
    int ky = rest % 37; int s = rest / 37;
    int m = l & 31, hi = l >> 5;
    int kk = 16 * t + 8 * hi + j - s;
    float v = 0.0f;
    if (m < 18 && kk >= 0 && kk < 37) v = wk[(m * 37 + ky) * 37 + kk];
    wshc[idx] = (ushort)f2bf(v);
    return;
  }

  const int w = tid >> 6;
  const int t = tid & 63;
  const int rowid = (g - PREP_BLOCKS) * 8 + w;     // [0, 6144)
  float* re  = smem + w * 256;
  float* im  = smem + 2048 + w * 256;
  float* twr = smem + 4096;
  float* twi = smem + 4224;

#pragma unroll
  for (int q = 0; q < 2; ++q) {
    int k = t + q * 64;
    float sn, cs;
    sincosf(-2.0f * (float)M_PI * (float)k / 256.0f, &sn, &cs);
    twr[k] = cs; twi[k] = sn;
  }
  const float* xr = x + (size_t)rowid * 256;
#pragma unroll
  for (int q = 0; q < 4; ++q) {
    int i = t + q * 64;
    int br = __brev((unsigned)i) >> 24;
    re[br] = xr[i];
    im[br] = 0.0f;
  }
  for (int s = 1; s <= 8; ++s) {
    int half = 1 << (s - 1);
    int sh = 8 - s;
#pragma unroll
    for (int q = 0; q < 2; ++q) {
      int j = t + q * 64;
      int gg = j >> (s - 1);
      int p = j & (half - 1);
      int i1 = (gg << s) + p;
      int i2 = i1 + half;
      float cs = twr[p << sh], sn = twi[p << sh];
      float r2 = re[i2], m2 = im[i2];
      float tr = r2 * cs - m2 * sn;
      float ti = r2 * sn + m2 * cs;
      float r1 = re[i1], m1 = im[i1];
      re[i2] = r1 - tr; im[i2] = m1 - ti;
      re[i1] = r1 + tr; im[i1] = m1 + ti;
    }
  }
  const int bc = rowid >> 8;                  // b*3 + c
  const int y  = rowid & 255;
  const int b  = bc / 3, c = bc - b * 3;
  float* magrow = out + FFT_OFF + (size_t)(b * 6 + c) * (HH * WW) + (size_t)y * WW;
  float* phrow  = magrow + (size_t)3 * (HH * WW);
#pragma unroll
  for (int q = 0; q < 2; ++q) {
    int k = t + q * 64;
    magrow[k] = re[k];
    phrow[k]  = im[k];
  }
  if (t == 0) { magrow[128] = re[128]; phrow[128] = im[128]; }
  // zero-fill pad cols 129..255 (read as zeros by edge panels; never
  // overwritten by pass B)
  magrow[129 + t] = 0.0f;
  phrow[129 + t]  = 0.0f;
  if (t < 63) {
    magrow[193 + t] = 0.0f;
    phrow[193 + t]  = 0.0f;
  }
}

// ================================================================ K2
// blocks [0,1536): Gabor conv via MFMA (R7/R14 structure, A ping-pong).
// blocks [1536,1944): column FFTs via coalesced 8-col LDS panels.
#define LOAD_B_SET \
    r0 = *reinterpret_cast<const bf16x8*>(bp); \
    r1 = *reinterpret_cast<const bf16x8*>(bp + 8); \
    r2 = *reinterpret_cast<const bf16x8*>(bp + 16); \
    r3 = *reinterpret_cast<const bf16x8*>(bp + 24); \
    r4 = *reinterpret_cast<const bf16x8*>(bp + 32); \
    r5 = *reinterpret_cast<const bf16x8*>(bp + 40); \
    r6 = *reinterpret_cast<const bf16x8*>(bp + 48); \
    r7 = *reinterpret_cast<const bf16x8*>(bp + 56);
#define MFMA_GROUP(A0, A1, A2) \
    acc0 = __builtin_amdgcn_mfma_f32_32x32x16_bf16(A0, r0, acc0, 0, 0, 0); \
    acc1 = __builtin_amdgcn_mfma_f32_32x32x16_bf16(A0, r1, acc1, 0, 0, 0); \
    acc2 = __builtin_amdgcn_mfma_f32_32x32x16_bf16(A0, r2, acc2, 0, 0, 0); \
    acc3 = __builtin_amdgcn_mfma_f32_32x32x16_bf16(A0, r3, acc3, 0, 0, 0); \
    acc0 = __builtin_amdgcn_mfma_f32_32x32x16_bf16(A1, r2, acc0, 0, 0, 0); \
    acc1 = __builtin_amdgcn_mfma_f32_32x32x16_bf16(A1, r3, acc1, 0, 0, 0); \
    acc2 = __builtin_amdgcn_mfma_f32_32x32x16_bf16(A1, r4, acc2, 0, 0, 0); \
    acc3 = __builtin_amdgcn_mfma_f32_32x32x16_bf16(A1, r5, acc3, 0, 0, 0); \
    acc0 = __builtin_amdgcn_mfma_f32_32x32x16_bf16(A2, r4, acc0, 0, 0, 0); \
    acc1 = __builtin_amdgcn_mfma_f32_32x32x16_bf16(A2, r5, acc1, 0, 0, 0); \
    acc2 = __builtin_amdgcn_mfma_f32_32x32x16_bf16(A2, r6, acc2, 0, 0, 0); \
    acc3 = __builtin_amdgcn_mfma_f32_32x32x16_bf16(A2, r7, acc3, 0, 0, 0);

__global__ __launch_bounds__(512, 4) void fused_main_kernel(
    const float* __restrict__ x, const ushort* __restrict__ wshc,
    float* __restrict__ out) {
  __shared__ __align__(16) float smem[7216];
  const int g = blockIdx.x;
  const int tid = threadIdx.x;

  if (g < GAB_BLOCKS) {
    // ------------------------------------------------ Gabor conv (MFMA)
    unsigned* patchU = reinterpret_cast<unsigned*>(smem);  // 68*44 uints
    float* cbuf = smem + 2992;                             // 4*32*33 floats
    const int tile = g & 63;
    const int rest = g >> 6;                               // [0,24)
    const int cin = rest % 3, b = rest / 3;
    const int tileX = (tile & 7) * 32;
    const int tileY = (tile >> 3) * 32;
    const float* xp = x + (size_t)(b * CC + cin) * (HH * WW);

    for (int idx = tid; idx < 68 * (PSTRIDE / 2); idx += 512) {
      int r = idx / (PSTRIDE / 2), dc = idx - r * (PSTRIDE / 2);
      int gy = tileY + r - PD;
      int gx0 = tileX + 2 * dc - PD;
      float v0 = 0.0f, v1 = 0.0f;
      if ((unsigned)gy < 256u) {
        if ((unsigned)gx0 < 256u)       v0 = xp[gy * WW + gx0];
        if ((unsigned)(gx0 + 1) < 256u) v1 = xp[gy * WW + gx0 + 1];
      }
      patchU[idx] = f2bf(v0) | (f2bf(v1) << 16);
    }
    __syncthreads();

    const int w  = tid >> 6;
    const int l  = tid & 63;
    const int n  = l & 31;
    const int hi = l >> 5;

    f32x16 acc0 = {0.f,0.f,0.f,0.f,0.f,0.f,0.f,0.f,0.f,0.f,0.f,0.f,0.f,0.f,0.f,0.f};
    f32x16 acc1 = acc0, acc2 = acc0, acc3 = acc0;

    const ushort* patchS = reinterpret_cast<const ushort*>(patchU);
    const ushort* ap = wshc + (size_t)w * (37 * 3 * 512) + (size_t)l * 8;
    const ushort* bp = patchS + (size_t)n * PSTRIDE + hi * 8;

    bf16x8 aA0, aA1, aA2, aB0, aB1, aB2;
    bf16x8 r0, r1, r2, r3, r4, r5, r6, r7;

    aA0 = *reinterpret_cast<const bf16x8*>(ap);
    aA1 = *reinterpret_cast<const bf16x8*>(ap + 512);
    aA2 = *reinterpret_cast<const bf16x8*>(ap + 1024);

    for (int kp = 0; kp < 18; ++kp) {
      aB0 = *reinterpret_cast<const bf16x8*>(ap + 1536);
      aB1 = *reinterpret_cast<const bf16x8*>(ap + 2048);
      aB2 = *reinterpret_cast<const bf16x8*>(ap + 2560);
      LOAD_B_SET
      MFMA_GROUP(aA0, aA1, aA2)
      bp += PSTRIDE;
      aA0 = *reinterpret_cast<const bf16x8*>(ap + 3072);
      aA1 = *reinterpret_cast<const bf16x8*>(ap + 3584);
      aA2 = *reinterpret_cast<const bf16x8*>(ap + 4096);
      LOAD_B_SET
      MFMA_GROUP(aB0, aB1, aB2)
      ap += 3072;
      bp += PSTRIDE;
    }
    {
      LOAD_B_SET
      MFMA_GROUP(aA0, aA1, aA2)
    }
    __syncthreads();

    float* outb = out + GAB_OFF + (size_t)(b * 54 + cin * 18) * (HH * WW);
#pragma unroll
    for (int gq = 0; gq < 5; ++gq) {
      if (hi == (gq & 1)) {
        const int rq = gq >> 1;
#pragma unroll
        for (int q = 0; q < 4; ++q) {
          const int e = 4 * rq + q;
          float* crow = &cbuf[(q * 32 + n) * 33 + w];
          crow[0]  = acc0[e];
          crow[8]  = acc1[e];
          crow[16] = acc2[e];
          crow[24] = acc3[e];
        }
      }
      __syncthreads();
#pragma unroll
      for (int it = 0; it < 8; ++it) {
        int idx = tid + it * 512;
        int xo = idx & 31, yo = (idx >> 5) & 31, q = idx >> 10;
        int f = 4 * gq + q;
        if (f < 18)
          outb[(size_t)f * (HH * WW) + (size_t)(tileY + yo) * WW + tileX + xo] =
              cbuf[(q * 32 + yo) * 33 + xo];
      }
      __syncthreads();
    }
    return;
  }

  // ---- column FFT + mag/phase via coalesced 8-col panels.
  // Block handles cols [8p, 8p+8) of one (b,c): stage panel in LDS with
  // coalesced 32B-chunk loads, per-wave FFT from LDS (wave-private),
  // mag/phase in place, coalesced masked store.
  const int pb  = g - GAB_BLOCKS;            // [0, 408)
  const int img = pb / 17;                   // [0, 24)
  const int pan = pb - img * 17;             // [0, 17)
  const int b = img / 3, c = img - b * 3;
  const int col0 = pan * 8;
  float* magp = out + FFT_OFF + (size_t)(b * 6 + c) * (HH * WW);
  float* php  = magp + (size_t)3 * (HH * WW);

  float* panRe = smem;                       // 8 x 257
  float* panIm = smem + 2056;                // 8 x 257
  float* twr   = smem + 4112;                // 128
  float* twi   = smem + 4240;                // 128

  if (tid < 128) {
    float sn, cs;
    sincosf(-2.0f * (float)M_PI * (float)tid / 256.0f, &sn, &cs);
    twr[tid] = cs; twi[tid] = sn;
  }
  const int rr = tid >> 3;                   // 0..63
  const int cc = tid & 7;
#pragma unroll
  for (int q = 0; q < 4; ++q) {
    int r = rr + q * 64;
    panRe[cc * 257 + r] = magp[(size_t)r * WW + col0 + cc];
    panIm[cc * 257 + r] = php [(size_t)r * WW + col0 + cc];
  }
  __syncthreads();

  const int w = tid >> 6;
  const int t = tid & 63;
  float* re = panRe + w * 257;
  float* im = panIm + w * 257;

  // in-panel bit-reversal (read-all then write-all; wave-lockstep safe)
  float vr[4], vi[4];
#pragma unroll
  for (int q = 0; q < 4; ++q) { vr[q] = re[t + q * 64]; vi[q] = im[t + q * 64]; }
#pragma unroll
  for (int q = 0; q < 4; ++q) {
    int br = __brev((unsigned)(t + q * 64)) >> 24;
    re[br] = vr[q]; im[br] = vi[q];
  }

  for (int s = 1; s <= 8; ++s) {
    int half = 1 << (s - 1);
    int sh = 8 - s;
#pragma unroll
    for (int q = 0; q < 2; ++q) {
      int j = t + q * 64;
      int gg = j >> (s - 1);
      int p = j & (half - 1);
      int i1 = (gg << s) + p;
      int i2 = i1 + half;
      float cs = twr[p << sh], sn = twi[p << sh];
      float r2 = re[i2], m2 = im[i2];
      float tr = r2 * cs - m2 * sn;
      float ti = r2 * sn + m2 * cs;
      float r1 = re[i1], m1 = im[i1];
      re[i2] = r1 - tr; im[i2] = m1 - ti;
      re[i1] = r1 + tr; im[i1] = m1 + ti;
    }
  }

  const float scale = 1.0f / 256.0f;   // ortho: /sqrt(256*256)
#pragma unroll
  for (int q = 0; q < 4; ++q) {
    int u = t + q * 64;
    float r = re[u], m = im[u];
    re[u] = sqrtf(r * r + m * m) * scale;
    im[u] = atan2f(m, r);
  }
  __syncthreads();

#pragma unroll
  for (int q = 0; q < 4; ++q) {
    int r = rr + q * 64;
    if (col0 + cc < 129) {
      magp[(size_t)r * WW + col0 + cc] = panRe[cc * 257 + r];
      php [(size_t)r * WW + col0 + cc] = panIm[cc * 257 + r];
    }
  }
}

// ================================================================ K3: DWT
__global__ __launch_bounds__(256) void haar_dwt_kernel(
    const float* __restrict__ x, float* __restrict__ out) {
  int idx = blockIdx.x * 256 + threadIdx.x;
  if (idx >= BB * CC * 128 * 128) return;
  int j  = idx & 127;
  int i  = (idx >> 7) & 127;
  int bc = idx >> 14;
  const float* xp = x + (size_t)bc * (HH * WW);
  float2 top = *reinterpret_cast<const float2*>(&xp[(2 * i) * WW + 2 * j]);
  float2 bot = *reinterpret_cast<const float2*>(&xp[(2 * i + 1) * WW + 2 * j]);
  float a = top.x, b = top.y, c = bot.x, d = bot.y;
  int bI = bc / 3, cI = bc % 3;
  float* op = out + DWT_OFF + ((size_t)(bI * 12 + cI * 4) * 128 + i) * 128 + j;
  op[0]     = (a + b + c + d) * 0.5f;
  op[16384] = (a + b - c - d) * 0.5f;
  op[32768] = (a - b + c - d) * 0.5f;
  op[49152] = (a - b - c + d) * 0.5f;
}

// ----------------------------------------------------------------
extern "C" void kernel_launch(void* const* d_in, const int* in_sizes, int n_in,
                              void* d_out, int out_size, void* d_ws, size_t ws_size,
                              hipStream_t stream) {
  const float* x  = (const float*)d_in[0];
  const float* wk = (const float*)d_in[1];
  float* out = (float*)d_out;

  // wshc scratch lives in the DWT output region; DWT (K3) runs last.
  ushort* wshc = (ushort*)(out + DWT_OFF);       // 909 KB

  fused_pre_kernel<<<dim3(PREP_BLOCKS + FFTROW_BLOCKS), dim3(512), 0, stream>>>(
      x, wk, wshc, out);
  fused_main_kernel<<<dim3(GAB_BLOCKS + FFTCOL_BLOCKS), dim3(512), 0, stream>>>(
      x, wshc, out);
  haar_dwt_kernel<<<dim3(1536), dim3(256), 0, stream>>>(x, out);
}